// Round 2
// baseline (1498.995 us; speedup 1.0000x reference)
//
#include <hip/hip_runtime.h>
#include <hip/hip_bf16.h>

#define BATCH 4
#define NPTS  8192
#define DIM   128
#define KNN   16
#define NROWS (BATCH * NPTS)   // 32768

using u64  = unsigned long long;
using u32  = unsigned int;

__device__ __forceinline__ unsigned short f2bf(float f) {
    u32 u = __float_as_uint(f);
    u32 r = (u + 0x7FFFu + ((u >> 16) & 1u)) >> 16;  // RTNE
    return (unsigned short)r;
}
// monotone float -> uint mapping (handles negatives, e.g. self-distance ~ -1e-7)
__device__ __forceinline__ u32 fordkey(float f) {
    u32 u = __float_as_uint(f);
    return (u & 0x80000000u) ? ~u : (u | 0x80000000u);
}

__device__ __forceinline__ void insert16(u64 key, u64* ks) {
    if (key < ks[15]) {
#pragma unroll
        for (int t = 0; t < 16; ++t) {
            u64 lo = key < ks[t] ? key : ks[t];
            u64 hi = key < ks[t] ? ks[t] : key;
            ks[t] = lo;
            key = hi;
        }
    }
}

// ---------------------------------------------------------------- weights prep
// wk[c] = sum_d Wk[c][d];  w2[c] = sum_d Wp2[c][d]
__global__ __launch_bounds__(256) void prep_weights(const float* __restrict__ Wk,
                                                    const float* __restrict__ Wp2,
                                                    float* __restrict__ wk,
                                                    float* __restrict__ w2) {
    int tid = threadIdx.x;
    int c = tid & 127;
    const float* src = (tid < 128) ? Wk : Wp2;
    float s = 0.f;
    for (int d = 0; d < DIM; ++d) s += src[c * DIM + d];
    if (tid < 128) wk[c] = s;
    else           w2[c] = s;
}

// ---------------------------------------------------------------- points prep
// pts[p] = (x,y,z, x^2+y^2+z^2) fp32 (numpy op order);  sK[p] = feat[p,:] . wk
__global__ __launch_bounds__(256) void prep_points(const float* __restrict__ xyz,
                                                   const float* __restrict__ feat,
                                                   const float* __restrict__ wk,
                                                   float4* __restrict__ pts,
                                                   float* __restrict__ sK) {
    int lid = threadIdx.x & 63;
    int p = blockIdx.x * 4 + (threadIdx.x >> 6);
    float f_lo = feat[(size_t)p * DIM + lid];
    float f_hi = feat[(size_t)p * DIM + 64 + lid];
    float s = fmaf(f_lo, wk[lid], f_hi * wk[64 + lid]);
#pragma unroll
    for (int m = 32; m >= 1; m >>= 1) s += __shfl_xor(s, m);
    if (lid == 0) {
        float x = xyz[p * 3 + 0];
        float y = xyz[p * 3 + 1];
        float z = xyz[p * 3 + 2];
        float sq = __fadd_rn(__fadd_rn(__fmul_rn(x, x), __fmul_rn(y, y)), __fmul_rn(z, z));
        pts[p] = make_float4(x, y, z, sq);
        sK[p] = s;
    }
}

// ---------------------------------------------------------------- KNN partial
// block = 64 threads = 64 queries (one wave); each block covers 1 of 4
// candidate ranges (2048 candidates). part layout: [(r*16+t)*NROWS + q]
__global__ __launch_bounds__(64) void knn_partial(const float4* __restrict__ pts,
                                                  u64* __restrict__ part) {
    int bid = blockIdx.x;
    int qblk = bid >> 2, r = bid & 3;
    int q = qblk * 64 + threadIdx.x;     // global point id
    int b = q >> 13;                     // batch (N=8192)
    float4 me = pts[q];
    __shared__ float4 tile[512];

    u64 ks[16];
#pragma unroll
    for (int t = 0; t < 16; ++t) ks[t] = ~0ull;

    int j0 = r * 2048;
    for (int tb = 0; tb < 4; ++tb) {
        __syncthreads();
        for (int i = threadIdx.x; i < 512; i += 64)
            tile[i] = pts[b * NPTS + j0 + tb * 512 + i];
        __syncthreads();
        int jb = j0 + tb * 512;
        for (int jj = 0; jj < 512; ++jj) {
            float4 c = tile[jj];
            // mirror numpy fp32 op order: (sq_i + sq_j) - 2*((xx+yy)+zz)
            float dot = __fadd_rn(__fadd_rn(__fmul_rn(me.x, c.x), __fmul_rn(me.y, c.y)),
                                  __fmul_rn(me.z, c.z));
            float d = __fsub_rn(__fadd_rn(me.w, c.w), __fmul_rn(2.0f, dot));
            u64 key = ((u64)fordkey(d) << 16) | (u32)(jb + jj);
            insert16(key, ks);
        }
    }
#pragma unroll
    for (int t = 0; t < 16; ++t)
        part[(size_t)(r * 16 + t) * NROWS + q] = ks[t];
}

// ---------------------------------------------------------------- KNN merge
__global__ __launch_bounds__(256) void knn_merge(const u64* __restrict__ part,
                                                 int* __restrict__ idx16) {
    int q = blockIdx.x * 256 + threadIdx.x;
    u64 ks[16];
#pragma unroll
    for (int t = 0; t < 16; ++t) ks[t] = ~0ull;
    for (int i = 0; i < 64; ++i)
        insert16(part[(size_t)i * NROWS + q], ks);
#pragma unroll
    for (int t = 0; t < 16; ++t)
        idx16[q * KNN + t] = (int)(ks[t] & 0xFFFFull);
}

// ---------------------------------------------------------------- GEMM 128x128
// X fp32, W fp32 (staged to bf16 in LDS), accum fp32.
// MODE 0: Vf   = X @ Wv + bv                      -> fp32
// MODE 1: T1   = X @ Wp2 + bp2 + add(vagg)        -> fp32
// MODE 2: out  = featb + gamma*(X @ Wo + bo)      -> fp32
template <int MODE>
__global__ __launch_bounds__(256) void gemm128(const float* __restrict__ X,
                                               const float* __restrict__ W,
                                               const float* __restrict__ bias,
                                               const float* __restrict__ add,
                                               const float* __restrict__ featb,
                                               const float* __restrict__ gammap,
                                               float* __restrict__ outv) {
    __shared__ unsigned short Ws[DIM * DIM];  // 32 KB bf16 bits
    __shared__ float Xs[8 * DIM];             // 4 KB
    __shared__ float bs[DIM];
    int tid = threadIdx.x;

    {   // stage W fp32 -> bf16 (RTNE), 4 at a time
        const float4* src = (const float4*)W;
        uint2* dst = (uint2*)Ws;
        for (int i = tid; i < DIM * DIM / 4; i += 256) {
            float4 w = src[i];
            uint2 o;
            o.x = (u32)f2bf(w.x) | ((u32)f2bf(w.y) << 16);
            o.y = (u32)f2bf(w.z) | ((u32)f2bf(w.w) << 16);
            dst[i] = o;
        }
    }
    if (tid < 128) bs[tid] = bias[tid];
    float gamma = 0.f;
    if (MODE == 2) gamma = *gammap;

    int rowBase = blockIdx.x * 128;
    int d4 = (tid & 31) * 4;
    int row = tid >> 5;  // 0..7

    for (int it = 0; it < 16; ++it) {
        int r0 = rowBase + it * 8;
        __syncthreads();
        // stage 8 rows of X (fp32)
        const float4* xs = (const float4*)(X + (size_t)r0 * DIM);
        ((float4*)Xs)[tid] = xs[tid];
        __syncthreads();

        float a0 = bs[d4], a1 = bs[d4 + 1], a2 = bs[d4 + 2], a3 = bs[d4 + 3];
        const float* xr = &Xs[row * DIM];
#pragma unroll 8
        for (int c = 0; c < DIM; ++c) {
            float x = xr[c];
            uint2 w = *(const uint2*)&Ws[c * DIM + d4];
            a0 = fmaf(x, __uint_as_float(w.x << 16), a0);
            a1 = fmaf(x, __uint_as_float(w.x & 0xFFFF0000u), a1);
            a2 = fmaf(x, __uint_as_float(w.y << 16), a2);
            a3 = fmaf(x, __uint_as_float(w.y & 0xFFFF0000u), a3);
        }
        size_t off = (size_t)(r0 + row) * DIM + d4;
        if (MODE == 1) {
            float4 ad = *(const float4*)(add + off);
            a0 += ad.x; a1 += ad.y; a2 += ad.z; a3 += ad.w;
        }
        if (MODE == 2) {
            float4 fb = *(const float4*)(featb + off);
            a0 = fmaf(gamma, a0, fb.x);
            a1 = fmaf(gamma, a1, fb.y);
            a2 = fmaf(gamma, a2, fb.z);
            a3 = fmaf(gamma, a3, fb.w);
        }
        *(float4*)(outv + off) = make_float4(a0, a1, a2, a3);
    }
}

// ---------------------------------------------------------------- stage C
// per point: h_k = relu(rel_k @ Wp1 + bp1); score_k = h_k.w2 - sK[j_k];
// softmax over 16 neighbors; vagg = sum attn*Vf[j]; hbar = sum attn*h_k
__global__ __launch_bounds__(256) void stage_c(const float4* __restrict__ pts,
                                               const int* __restrict__ idx16,
                                               const float* __restrict__ sK,
                                               const float* __restrict__ w2,
                                               const float* __restrict__ Wp1,
                                               const float* __restrict__ bp1,
                                               const float* __restrict__ Vf,
                                               float* __restrict__ vagg,
                                               float* __restrict__ hbar) {
    __shared__ float hs[4][KNN * DIM];  // 32 KB
    int wavein = threadIdx.x >> 6;
    int lid = threadIdx.x & 63;
    int p = blockIdx.x * 4 + wavein;
    int b = p >> 13;
    float4 me = pts[p];

    float wx_lo = Wp1[lid],        wx_hi = Wp1[64 + lid];
    float wy_lo = Wp1[128 + lid],  wy_hi = Wp1[192 + lid];
    float wz_lo = Wp1[256 + lid],  wz_hi = Wp1[320 + lid];
    float bl    = bp1[lid],        bh    = bp1[64 + lid];
    float w2l   = w2[lid],         w2h   = w2[64 + lid];

    int myidx = idx16[p * KNN + (lid & 15)];
    float* h = hs[wavein];
    float sc = -INFINITY;

    for (int k = 0; k < KNN; ++k) {
        int j = __shfl(myidx, k);
        int g = b * NPTS + j;
        float4 nb = pts[g];
        float rx = me.x - nb.x, ry = me.y - nb.y, rz = me.z - nb.z;
        float h_lo = fmaxf(0.f, fmaf(rx, wx_lo, fmaf(ry, wy_lo, fmaf(rz, wz_lo, bl))));
        float h_hi = fmaxf(0.f, fmaf(rx, wx_hi, fmaf(ry, wy_hi, fmaf(rz, wz_hi, bh))));
        h[k * DIM + lid] = h_lo;
        h[k * DIM + 64 + lid] = h_hi;
        float s = fmaf(h_lo, w2l, h_hi * w2h);
#pragma unroll
        for (int m = 32; m >= 1; m >>= 1) s += __shfl_xor(s, m);
        float score = s - sK[g];
        if (lid == k) sc = score;
    }
    // softmax over lanes 0..15 (16-lane subgroup reductions)
    float mx = sc;
#pragma unroll
    for (int m = 8; m >= 1; m >>= 1) mx = fmaxf(mx, __shfl_xor(mx, m));
    float e = (lid < 16) ? __expf(sc - mx) : 0.f;
    float ssum = e;
#pragma unroll
    for (int m = 8; m >= 1; m >>= 1) ssum += __shfl_xor(ssum, m);
    float a = e / ssum;   // valid on lanes 0..15; only those are shfl-read below

    float acc_lo = 0.f, acc_hi = 0.f, hb_lo = 0.f, hb_hi = 0.f;
    for (int k = 0; k < KNN; ++k) {
        float ak = __shfl(a, k);
        int j = __shfl(myidx, k);
        size_t g = (size_t)(b * NPTS + j) * DIM;
        acc_lo = fmaf(ak, Vf[g + lid], acc_lo);
        acc_hi = fmaf(ak, Vf[g + 64 + lid], acc_hi);
        hb_lo = fmaf(ak, h[k * DIM + lid], hb_lo);
        hb_hi = fmaf(ak, h[k * DIM + 64 + lid], hb_hi);
    }
    size_t o = (size_t)p * DIM;
    vagg[o + lid] = acc_lo;
    vagg[o + 64 + lid] = acc_hi;
    hbar[o + lid] = hb_lo;
    hbar[o + 64 + lid] = hb_hi;
}

// ---------------------------------------------------------------- launcher
extern "C" void kernel_launch(void* const* d_in, const int* in_sizes, int n_in,
                              void* d_out, int out_size, void* d_ws, size_t ws_size,
                              hipStream_t stream) {
    const float* xyz   = (const float*)d_in[0];
    const float* feat  = (const float*)d_in[1];
    // d_in[2]=Wq, d_in[3]=bq, d_in[5]=bk: provably irrelevant (softmax shift-invariance)
    const float* Wk    = (const float*)d_in[4];
    const float* Wv    = (const float*)d_in[6];
    const float* bv    = (const float*)d_in[7];
    const float* Wp1   = (const float*)d_in[8];
    const float* bp1   = (const float*)d_in[9];
    const float* Wp2   = (const float*)d_in[10];
    const float* bp2   = (const float*)d_in[11];
    const float* Wo    = (const float*)d_in[12];
    const float* bo    = (const float*)d_in[13];
    const float* gamma = (const float*)d_in[14];
    float* out = (float*)d_out;

    char* ws = (char*)d_ws;
    const size_t MB = 1024 * 1024;
    float*  wk    = (float*)(ws + 0);
    float*  w2    = (float*)(ws + 4096);
    float4* pts   = (float4*)(ws + 16 * 1024);   // 512 KB
    float*  sKv   = (float*)(ws + 1 * MB);       // 128 KB
    u64*    part  = (u64*)(ws + 2 * MB);         // 16 MB, consumed by knn_merge
    float*  vagg  = (float*)(ws + 2 * MB);       // aliases part (written after merge)
    int*    idx16 = (int*)(ws + 18 * MB);        // 2 MB
    float*  Vf    = (float*)(ws + 20 * MB);      // 16 MB, dead after stage_c
    float*  T1    = (float*)(ws + 20 * MB);      // aliases Vf (written by gemm<1>)
    float*  hbarp = (float*)(ws + 36 * MB);      // 16 MB  (total 52 MB)

    prep_weights<<<1, 256, 0, stream>>>(Wk, Wp2, wk, w2);
    prep_points<<<NROWS / 4, 256, 0, stream>>>(xyz, feat, wk, pts, sKv);
    gemm128<0><<<256, 256, 0, stream>>>(feat, Wv, bv, nullptr, nullptr, nullptr, Vf);
    knn_partial<<<(NROWS / 64) * 4, 64, 0, stream>>>(pts, part);
    knn_merge<<<NROWS / 256, 256, 0, stream>>>(part, idx16);
    stage_c<<<NROWS / 4, 256, 0, stream>>>(pts, idx16, sKv, w2, Wp1, bp1, Vf, vagg, hbarp);
    gemm128<1><<<256, 256, 0, stream>>>(hbarp, Wp2, bp2, vagg, nullptr, nullptr, T1);
    gemm128<2><<<256, 256, 0, stream>>>(T1, Wo, bo, nullptr, feat, gamma, out);
}

// Round 3
// 812.670 us; speedup vs baseline: 1.8445x; 1.8445x over previous
//
#include <hip/hip_runtime.h>
#include <hip/hip_bf16.h>

#define BATCH 4
#define NPTS  8192
#define DIM   128
#define KNN   16
#define NROWS (BATCH * NPTS)   // 32768

#define SPLITS 8
#define SPLITC (NPTS / SPLITS) // 1024 candidates per split
#define TILE   256             // candidates per LDS tile (drain granularity)
#define DEPTH  48              // per-lane pending stack depth

using u64  = unsigned long long;
using u32  = unsigned int;

__device__ __forceinline__ unsigned short f2bf(float f) {
    u32 u = __float_as_uint(f);
    u32 r = (u + 0x7FFFu + ((u >> 16) & 1u)) >> 16;  // RTNE
    return (unsigned short)r;
}
// monotone float -> uint mapping (handles negatives, e.g. self-distance ~ -1e-7)
__device__ __forceinline__ u32 fordkey(float f) {
    u32 u = __float_as_uint(f);
    return (u & 0x80000000u) ? ~u : (u | 0x80000000u);
}

__device__ __forceinline__ void insert16(u64 key, u64* ks) {
    if (key < ks[15]) {
#pragma unroll
        for (int t = 0; t < 16; ++t) {
            u64 lo = key < ks[t] ? key : ks[t];
            u64 hi = key < ks[t] ? ks[t] : key;
            ks[t] = lo;
            key = hi;
        }
    }
}

// exact numpy fp32 op order: (sq_i + sq_j) - 2*((xx+yy)+zz)   [proven in R2]
__device__ __forceinline__ float pdist(float4 me, float4 c) {
    float dot = __fadd_rn(__fadd_rn(__fmul_rn(me.x, c.x), __fmul_rn(me.y, c.y)),
                          __fmul_rn(me.z, c.z));
    return __fsub_rn(__fadd_rn(me.w, c.w), __fmul_rn(2.0f, dot));
}

// ---------------------------------------------------------------- weights prep
__global__ __launch_bounds__(256) void prep_weights(const float* __restrict__ Wk,
                                                    const float* __restrict__ Wp2,
                                                    float* __restrict__ wk,
                                                    float* __restrict__ w2) {
    int tid = threadIdx.x;
    int c = tid & 127;
    const float* src = (tid < 128) ? Wk : Wp2;
    float s = 0.f;
    for (int d = 0; d < DIM; ++d) s += src[c * DIM + d];
    if (tid < 128) wk[c] = s;
    else           w2[c] = s;
}

// ---------------------------------------------------------------- points prep
__global__ __launch_bounds__(256) void prep_points(const float* __restrict__ xyz,
                                                   const float* __restrict__ feat,
                                                   const float* __restrict__ wk,
                                                   float4* __restrict__ pts,
                                                   float* __restrict__ sK) {
    int lid = threadIdx.x & 63;
    int p = blockIdx.x * 4 + (threadIdx.x >> 6);
    float f_lo = feat[(size_t)p * DIM + lid];
    float f_hi = feat[(size_t)p * DIM + 64 + lid];
    float s = fmaf(f_lo, wk[lid], f_hi * wk[64 + lid]);
#pragma unroll
    for (int m = 32; m >= 1; m >>= 1) s += __shfl_xor(s, m);
    if (lid == 0) {
        float x = xyz[p * 3 + 0];
        float y = xyz[p * 3 + 1];
        float z = xyz[p * 3 + 2];
        float sq = __fadd_rn(__fadd_rn(__fmul_rn(x, x), __fmul_rn(y, y)), __fmul_rn(z, z));
        pts[p] = make_float4(x, y, z, sq);
        sK[p] = s;
    }
}

// ---------------------------------------------------------------- KNN prepass
// Tq[q] = 16th-smallest key over candidates [0,256) of q's batch — a valid
// upper bound on the true 16th-NN key (top-k of a subset >= top-k of set).
__global__ __launch_bounds__(256) void knn_prepass(const float4* __restrict__ pts,
                                                   u64* __restrict__ Tq) {
    __shared__ float4 tile[256];
    int q = blockIdx.x * 256 + threadIdx.x;
    int b = q >> 13;  // uniform within block (256 | 8192)
    float4 me = pts[q];
    tile[threadIdx.x] = pts[b * NPTS + threadIdx.x];
    __syncthreads();
    u64 ks[16];
#pragma unroll
    for (int t = 0; t < 16; ++t) ks[t] = ~0ull;
    for (int jj = 0; jj < 256; ++jj) {
        float d = pdist(me, tile[jj]);
        u64 key = ((u64)fordkey(d) << 16) | (u32)jj;
        insert16(key, ks);
    }
    Tq[q] = ks[15];
}

// ---------------------------------------------------------------- KNN partial
// 1 wave = 64 queries; 8 splits of 1024 candidates. Passing candidates are
// deferred to a per-lane LDS stack (u16 tile-local idx) and bulk-drained per
// 256-candidate tile; overflow falls back to exact direct insert.
__global__ __launch_bounds__(64) void knn_partial(const float4* __restrict__ pts,
                                                  const u64* __restrict__ Tq,
                                                  u64* __restrict__ part) {
    __shared__ float4 tile[TILE];                 // 4 KB
    __shared__ unsigned short stk[DEPTH][64];     // 6 KB
    int bid = blockIdx.x;
    int qblk = bid >> 3, r = bid & 7;
    int lane = threadIdx.x;
    int q = qblk * 64 + lane;
    int b = q >> 13;
    float4 me = pts[q];

    u64 ks[16];
#pragma unroll
    for (int t = 0; t < 16; ++t) ks[t] = ~0ull;
    u64 lim = Tq[q];
    int cnt = 0;

    for (int tb = 0; tb < SPLITC / TILE; ++tb) {
        __syncthreads();
        int jb = r * SPLITC + tb * TILE;
        for (int i = lane; i < TILE; i += 64)
            tile[i] = pts[b * NPTS + jb + i];
        __syncthreads();

        for (int jj = 0; jj < TILE; ++jj) {
            float d = pdist(me, tile[jj]);
            u64 key = ((u64)fordkey(d) << 16) | (u32)(jb + jj);
            if (key <= lim) {                      // <=: keep the Tq element itself
                if (cnt < DEPTH) { stk[cnt][lane] = (unsigned short)jj; cnt++; }
                else insert16(key, ks);            // rare overflow: exact fallback
            }
        }
        // drain pending (wave runs max(cnt) exec-masked iterations)
        for (int i = 0; i < cnt; ++i) {
            int jj = stk[i][lane];
            float d = pdist(me, tile[jj]);
            u64 key = ((u64)fordkey(d) << 16) | (u32)(jb + jj);
            insert16(key, ks);
        }
        cnt = 0;
        u64 k15 = ks[15];
        lim = (k15 < lim) ? k15 : lim;
    }
#pragma unroll
    for (int t = 0; t < 16; ++t)
        part[(size_t)(r * 16 + t) * NROWS + q] = ks[t];
}

// ---------------------------------------------------------------- KNN merge
__global__ __launch_bounds__(256) void knn_merge(const u64* __restrict__ part,
                                                 int* __restrict__ idx16) {
    int q = blockIdx.x * 256 + threadIdx.x;
    u64 ks[16];
#pragma unroll
    for (int t = 0; t < 16; ++t) ks[t] = ~0ull;
    for (int i = 0; i < SPLITS * 16; ++i)
        insert16(part[(size_t)i * NROWS + q], ks);
#pragma unroll
    for (int t = 0; t < 16; ++t)
        idx16[q * KNN + t] = (int)(ks[t] & 0xFFFFull);
}

// ---------------------------------------------------------------- GEMM 128x128
// X fp32, W fp32 (staged to bf16 in LDS), accum fp32.
// MODE 0: Vf   = X @ Wv + bv                      -> fp32
// MODE 1: T1   = X @ Wp2 + bp2 + add(vagg)        -> fp32
// MODE 2: out  = featb + gamma*(X @ Wo + bo)      -> fp32
template <int MODE>
__global__ __launch_bounds__(256) void gemm128(const float* __restrict__ X,
                                               const float* __restrict__ W,
                                               const float* __restrict__ bias,
                                               const float* __restrict__ add,
                                               const float* __restrict__ featb,
                                               const float* __restrict__ gammap,
                                               float* __restrict__ outv) {
    __shared__ unsigned short Ws[DIM * DIM];  // 32 KB bf16 bits
    __shared__ float Xs[8 * DIM];             // 4 KB
    __shared__ float bs[DIM];
    int tid = threadIdx.x;

    {   // stage W fp32 -> bf16 (RTNE)
        const float4* src = (const float4*)W;
        uint2* dst = (uint2*)Ws;
        for (int i = tid; i < DIM * DIM / 4; i += 256) {
            float4 w = src[i];
            uint2 o;
            o.x = (u32)f2bf(w.x) | ((u32)f2bf(w.y) << 16);
            o.y = (u32)f2bf(w.z) | ((u32)f2bf(w.w) << 16);
            dst[i] = o;
        }
    }
    if (tid < 128) bs[tid] = bias[tid];
    float gamma = 0.f;
    if (MODE == 2) gamma = *gammap;

    int rowBase = blockIdx.x * 128;
    int d4 = (tid & 31) * 4;
    int row = tid >> 5;  // 0..7

    for (int it = 0; it < 16; ++it) {
        int r0 = rowBase + it * 8;
        __syncthreads();
        const float4* xs = (const float4*)(X + (size_t)r0 * DIM);
        ((float4*)Xs)[tid] = xs[tid];
        __syncthreads();

        float a0 = bs[d4], a1 = bs[d4 + 1], a2 = bs[d4 + 2], a3 = bs[d4 + 3];
        const float* xr = &Xs[row * DIM];
#pragma unroll 8
        for (int c = 0; c < DIM; ++c) {
            float x = xr[c];
            uint2 w = *(const uint2*)&Ws[c * DIM + d4];
            a0 = fmaf(x, __uint_as_float(w.x << 16), a0);
            a1 = fmaf(x, __uint_as_float(w.x & 0xFFFF0000u), a1);
            a2 = fmaf(x, __uint_as_float(w.y << 16), a2);
            a3 = fmaf(x, __uint_as_float(w.y & 0xFFFF0000u), a3);
        }
        size_t off = (size_t)(r0 + row) * DIM + d4;
        if (MODE == 1) {
            float4 ad = *(const float4*)(add + off);
            a0 += ad.x; a1 += ad.y; a2 += ad.z; a3 += ad.w;
        }
        if (MODE == 2) {
            float4 fb = *(const float4*)(featb + off);
            a0 = fmaf(gamma, a0, fb.x);
            a1 = fmaf(gamma, a1, fb.y);
            a2 = fmaf(gamma, a2, fb.z);
            a3 = fmaf(gamma, a3, fb.w);
        }
        *(float4*)(outv + off) = make_float4(a0, a1, a2, a3);
    }
}

// ---------------------------------------------------------------- stage C
__global__ __launch_bounds__(256) void stage_c(const float4* __restrict__ pts,
                                               const int* __restrict__ idx16,
                                               const float* __restrict__ sK,
                                               const float* __restrict__ w2,
                                               const float* __restrict__ Wp1,
                                               const float* __restrict__ bp1,
                                               const float* __restrict__ Vf,
                                               float* __restrict__ vagg,
                                               float* __restrict__ hbar) {
    __shared__ float hs[4][KNN * DIM];  // 32 KB
    int wavein = threadIdx.x >> 6;
    int lid = threadIdx.x & 63;
    int p = blockIdx.x * 4 + wavein;
    int b = p >> 13;
    float4 me = pts[p];

    float wx_lo = Wp1[lid],        wx_hi = Wp1[64 + lid];
    float wy_lo = Wp1[128 + lid],  wy_hi = Wp1[192 + lid];
    float wz_lo = Wp1[256 + lid],  wz_hi = Wp1[320 + lid];
    float bl    = bp1[lid],        bh    = bp1[64 + lid];
    float w2l   = w2[lid],         w2h   = w2[64 + lid];

    int myidx = idx16[p * KNN + (lid & 15)];
    float* h = hs[wavein];
    float sc = -INFINITY;

    for (int k = 0; k < KNN; ++k) {
        int j = __shfl(myidx, k);
        int g = b * NPTS + j;
        float4 nb = pts[g];
        float rx = me.x - nb.x, ry = me.y - nb.y, rz = me.z - nb.z;
        float h_lo = fmaxf(0.f, fmaf(rx, wx_lo, fmaf(ry, wy_lo, fmaf(rz, wz_lo, bl))));
        float h_hi = fmaxf(0.f, fmaf(rx, wx_hi, fmaf(ry, wy_hi, fmaf(rz, wz_hi, bh))));
        h[k * DIM + lid] = h_lo;
        h[k * DIM + 64 + lid] = h_hi;
        float s = fmaf(h_lo, w2l, h_hi * w2h);
#pragma unroll
        for (int m = 32; m >= 1; m >>= 1) s += __shfl_xor(s, m);
        float score = s - sK[g];
        if (lid == k) sc = score;
    }
    float mx = sc;
#pragma unroll
    for (int m = 8; m >= 1; m >>= 1) mx = fmaxf(mx, __shfl_xor(mx, m));
    float e = (lid < 16) ? __expf(sc - mx) : 0.f;
    float ssum = e;
#pragma unroll
    for (int m = 8; m >= 1; m >>= 1) ssum += __shfl_xor(ssum, m);
    float a = e / ssum;

    float acc_lo = 0.f, acc_hi = 0.f, hb_lo = 0.f, hb_hi = 0.f;
    for (int k = 0; k < KNN; ++k) {
        float ak = __shfl(a, k);
        int j = __shfl(myidx, k);
        size_t g = (size_t)(b * NPTS + j) * DIM;
        acc_lo = fmaf(ak, Vf[g + lid], acc_lo);
        acc_hi = fmaf(ak, Vf[g + 64 + lid], acc_hi);
        hb_lo = fmaf(ak, h[k * DIM + lid], hb_lo);
        hb_hi = fmaf(ak, h[k * DIM + 64 + lid], hb_hi);
    }
    size_t o = (size_t)p * DIM;
    vagg[o + lid] = acc_lo;
    vagg[o + 64 + lid] = acc_hi;
    hbar[o + lid] = hb_lo;
    hbar[o + 64 + lid] = hb_hi;
}

// ---------------------------------------------------------------- launcher
extern "C" void kernel_launch(void* const* d_in, const int* in_sizes, int n_in,
                              void* d_out, int out_size, void* d_ws, size_t ws_size,
                              hipStream_t stream) {
    const float* xyz   = (const float*)d_in[0];
    const float* feat  = (const float*)d_in[1];
    // d_in[2]=Wq, d_in[3]=bq, d_in[5]=bk: provably irrelevant (softmax shift-invariance)
    const float* Wk    = (const float*)d_in[4];
    const float* Wv    = (const float*)d_in[6];
    const float* bv    = (const float*)d_in[7];
    const float* Wp1   = (const float*)d_in[8];
    const float* bp1   = (const float*)d_in[9];
    const float* Wp2   = (const float*)d_in[10];
    const float* bp2   = (const float*)d_in[11];
    const float* Wo    = (const float*)d_in[12];
    const float* bo    = (const float*)d_in[13];
    const float* gamma = (const float*)d_in[14];
    float* out = (float*)d_out;

    char* ws = (char*)d_ws;
    const size_t MB = 1024 * 1024;
    float*  wk    = (float*)(ws + 0);
    float*  w2    = (float*)(ws + 4096);
    float4* pts   = (float4*)(ws + 16 * 1024);       // 512 KB
    float*  sKv   = (float*)(ws + 1 * MB);           // 128 KB
    u64*    Tq    = (u64*)(ws + MB + MB / 2);        // 256 KB
    u64*    part  = (u64*)(ws + 2 * MB);             // 32 MB (8 splits x 16)
    float*  vagg  = (float*)(ws + 2 * MB);           // aliases part (after merge)
    int*    idx16 = (int*)(ws + 34 * MB);            // 2 MB
    float*  Vf    = (float*)(ws + 36 * MB);          // 16 MB, dead after stage_c
    float*  T1    = (float*)(ws + 36 * MB);          // aliases Vf
    float*  hbarp = (float*)(ws + 52 * MB);          // 16 MB (total 68 MB)

    prep_weights<<<1, 256, 0, stream>>>(Wk, Wp2, wk, w2);
    prep_points<<<NROWS / 4, 256, 0, stream>>>(xyz, feat, wk, pts, sKv);
    gemm128<0><<<256, 256, 0, stream>>>(feat, Wv, bv, nullptr, nullptr, nullptr, Vf);
    knn_prepass<<<NROWS / 256, 256, 0, stream>>>(pts, Tq);
    knn_partial<<<(NROWS / 64) * SPLITS, 64, 0, stream>>>(pts, Tq, part);
    knn_merge<<<NROWS / 256, 256, 0, stream>>>(part, idx16);
    stage_c<<<NROWS / 4, 256, 0, stream>>>(pts, idx16, sKv, w2, Wp1, bp1, Vf, vagg, hbarp);
    gemm128<1><<<256, 256, 0, stream>>>(hbarp, Wp2, bp2, vagg, nullptr, nullptr, T1);
    gemm128<2><<<256, 256, 0, stream>>>(T1, Wo, bo, nullptr, feat, gamma, out);
}

// Round 4
// 740.986 us; speedup vs baseline: 2.0230x; 1.0967x over previous
//
#include <hip/hip_runtime.h>
#include <hip/hip_bf16.h>

#define BATCH 4
#define NPTS  8192
#define DIM   128
#define KNN   16
#define NROWS (BATCH * NPTS)   // 32768

#define SPLITS 8
#define SPLITC (NPTS / SPLITS) // 1024 candidates per split
#define TILE   256             // candidates per LDS tile (drain granularity)
#define DEPTH  48              // per-lane pending stack depth

using u64  = unsigned long long;
using u32  = unsigned int;

__device__ __forceinline__ unsigned short f2bf(float f) {
    u32 u = __float_as_uint(f);
    u32 r = (u + 0x7FFFu + ((u >> 16) & 1u)) >> 16;  // RTNE
    return (unsigned short)r;
}
// monotone float -> uint mapping (handles negatives, e.g. self-distance ~ -1e-7)
__device__ __forceinline__ u32 fordkey(float f) {
    u32 u = __float_as_uint(f);
    return (u & 0x80000000u) ? ~u : (u | 0x80000000u);
}

__device__ __forceinline__ void insert16(u64 key, u64* ks) {
    if (key < ks[15]) {
#pragma unroll
        for (int t = 0; t < 16; ++t) {
            u64 lo = key < ks[t] ? key : ks[t];
            u64 hi = key < ks[t] ? ks[t] : key;
            ks[t] = lo;
            key = hi;
        }
    }
}

// exact numpy fp32 op order: (sq_i + sq_j) - 2*((xx+yy)+zz)   [proven in R2]
__device__ __forceinline__ float pdist(float4 me, float4 c) {
    float dot = __fadd_rn(__fadd_rn(__fmul_rn(me.x, c.x), __fmul_rn(me.y, c.y)),
                          __fmul_rn(me.z, c.z));
    return __fsub_rn(__fadd_rn(me.w, c.w), __fmul_rn(2.0f, dot));
}

// ---------------------------------------------------------------- weights prep
// wk[c] = sum_d Wk[c][d];  w2[c] = sum_d Wp2[c][d]
__global__ __launch_bounds__(256) void prep_weights(const float* __restrict__ Wk,
                                                    const float* __restrict__ Wp2,
                                                    float* __restrict__ wk,
                                                    float* __restrict__ w2) {
    int tid = threadIdx.x;
    int c = tid & 127;
    const float* src = (tid < 128) ? Wk : Wp2;
    float s = 0.f;
    for (int d = 0; d < DIM; ++d) s += src[c * DIM + d];
    if (tid < 128) wk[c] = s;
    else           w2[c] = s;
}

// convert Wv / Wp2 / Wo to packed bf16 pairs, once (L2-resident afterwards)
__global__ __launch_bounds__(256) void conv_weights(const float* __restrict__ Wv,
                                                    const float* __restrict__ Wp2,
                                                    const float* __restrict__ Wo,
                                                    u32* __restrict__ Wb) {
    int i = blockIdx.x * 256 + threadIdx.x;   // 0 .. 3*8192-1
    int which = i >> 13, off = i & 8191;
    const float* W = (which == 0) ? Wv : (which == 1 ? Wp2 : Wo);
    float2 w = ((const float2*)W)[off];
    Wb[i] = (u32)f2bf(w.x) | ((u32)f2bf(w.y) << 16);
}

// ---------------------------------------------------------------- points prep
__global__ __launch_bounds__(256) void prep_points(const float* __restrict__ xyz,
                                                   const float* __restrict__ feat,
                                                   const float* __restrict__ wk,
                                                   float4* __restrict__ pts,
                                                   float* __restrict__ sK) {
    int lid = threadIdx.x & 63;
    int p = blockIdx.x * 4 + (threadIdx.x >> 6);
    float f_lo = feat[(size_t)p * DIM + lid];
    float f_hi = feat[(size_t)p * DIM + 64 + lid];
    float s = fmaf(f_lo, wk[lid], f_hi * wk[64 + lid]);
#pragma unroll
    for (int m = 32; m >= 1; m >>= 1) s += __shfl_xor(s, m);
    if (lid == 0) {
        float x = xyz[p * 3 + 0];
        float y = xyz[p * 3 + 1];
        float z = xyz[p * 3 + 2];
        float sq = __fadd_rn(__fadd_rn(__fmul_rn(x, x), __fmul_rn(y, y)), __fmul_rn(z, z));
        pts[p] = make_float4(x, y, z, sq);
        sK[p] = s;
    }
}

// ---------------------------------------------------------------- KNN prepass
// seeds[t][q], t=0..15: exact top-16 keys over candidates [0,256) of q's
// batch. seeds[15] is a valid upper bound on the true 16th-NN key.
__global__ __launch_bounds__(256) void knn_prepass(const float4* __restrict__ pts,
                                                   u64* __restrict__ seeds) {
    __shared__ float4 tile[256];
    int q = blockIdx.x * 256 + threadIdx.x;
    int b = q >> 13;  // uniform within block (256 | 8192)
    float4 me = pts[q];
    tile[threadIdx.x] = pts[b * NPTS + threadIdx.x];
    __syncthreads();
    u64 ks[16];
#pragma unroll
    for (int t = 0; t < 16; ++t) ks[t] = ~0ull;
    for (int jj = 0; jj < 256; ++jj) {
        float d = pdist(me, tile[jj]);
        u64 key = ((u64)fordkey(d) << 16) | (u32)jj;
        insert16(key, ks);
    }
#pragma unroll
    for (int t = 0; t < 16; ++t) seeds[t * NROWS + q] = ks[t];
}

// ---------------------------------------------------------------- KNN partial
// 256 thr = 4 query-waves sharing the candidate tile; 8 splits of 1024.
// Splits 1..7 seed their chain with the prepass top-16 so lim ratchets from
// candidate 0; they emit only own-range entries (idx>=256) — split 0 owns
// the seed range. Union provably covers the global top-16, ranges disjoint.
__global__ __launch_bounds__(256) void knn_partial(const float4* __restrict__ pts,
                                                   const u64* __restrict__ seeds,
                                                   u64* __restrict__ part) {
    __shared__ float4 tile[TILE];                    // 4 KB
    __shared__ unsigned short stk[4][DEPTH][64];     // 24 KB
    int bid = blockIdx.x;
    int qblk = bid >> 3, r = bid & 7;
    int wavein = threadIdx.x >> 6, lane = threadIdx.x & 63;
    int q = qblk * 256 + wavein * 64 + lane;
    int b = q >> 13;
    float4 me = pts[q];

    u64 ks[16];
    u64 lim;
    if (r == 0) {
#pragma unroll
        for (int t = 0; t < 16; ++t) ks[t] = ~0ull;
        lim = seeds[15 * NROWS + q];
    } else {
#pragma unroll
        for (int t = 0; t < 16; ++t) ks[t] = seeds[t * NROWS + q];
        lim = ks[15];
    }
    int cnt = 0;
    unsigned short (*mystk)[64] = stk[wavein];

    for (int tb = 0; tb < SPLITC / TILE; ++tb) {
        __syncthreads();
        int jb = r * SPLITC + tb * TILE;
        tile[threadIdx.x] = pts[b * NPTS + jb + threadIdx.x];
        __syncthreads();

        for (int jj = 0; jj < TILE; ++jj) {
            float d = pdist(me, tile[jj]);
            u64 key = ((u64)fordkey(d) << 16) | (u32)(jb + jj);
            if (key <= lim) {
                if (cnt < DEPTH) { mystk[cnt][lane] = (unsigned short)jj; cnt++; }
                else insert16(key, ks);            // rare overflow: exact fallback
            }
        }
        // drain pending (per-wave, exec-masked to max(cnt) iterations)
        for (int i = 0; i < cnt; ++i) {
            int jj = mystk[i][lane];
            float d = pdist(me, tile[jj]);
            u64 key = ((u64)fordkey(d) << 16) | (u32)(jb + jj);
            insert16(key, ks);
        }
        cnt = 0;
        u64 k15 = ks[15];
        lim = (k15 < lim) ? k15 : lim;
    }
#pragma unroll
    for (int t = 0; t < 16; ++t) {
        u64 v = ks[t];
        if (r != 0 && (v & 0xFFFFull) < 256) v = ~0ull;  // seed entry: split 0 owns it
        part[(size_t)(r * 16 + t) * NROWS + q] = v;
    }
}

// ---------------------------------------------------------------- KNN merge
__global__ __launch_bounds__(256) void knn_merge(const u64* __restrict__ part,
                                                 int* __restrict__ idx16) {
    int q = blockIdx.x * 256 + threadIdx.x;
    u64 ks[16];
#pragma unroll
    for (int t = 0; t < 16; ++t) ks[t] = ~0ull;
    for (int i = 0; i < SPLITS * 16; ++i)
        insert16(part[(size_t)i * NROWS + q], ks);
#pragma unroll
    for (int t = 0; t < 16; ++t)
        idx16[q * KNN + t] = (int)(ks[t] & 0xFFFFull);
}

// ---------------------------------------------------------------- GEMM 32-row
// X fp32, W pre-packed bf16 pairs (global, staged to LDS), accum fp32.
// grid 1024 x 256thr -> 4 blocks/CU (36.5 KB LDS), 16 waves/CU.
// MODE 0: Vf   = X @ Wv + bv                      -> fp32
// MODE 1: T1   = X @ Wp2 + bp2 + add(vagg)        -> fp32
// MODE 2: out  = featb + gamma*(X @ Wo + bo)      -> fp32
template <int MODE>
__global__ __launch_bounds__(256) void gemm32(const float* __restrict__ X,
                                              const u32* __restrict__ Wb,
                                              const float* __restrict__ bias,
                                              const float* __restrict__ add,
                                              const float* __restrict__ featb,
                                              const float* __restrict__ gammap,
                                              float* __restrict__ outv) {
    __shared__ u32 Ws[DIM * DIM / 2];   // 32 KB packed bf16 pairs, [c][d/2]
    __shared__ float Xs[8 * DIM];       // 4 KB
    __shared__ float bs[DIM];
    int tid = threadIdx.x;
    {
        const uint4* src = (const uint4*)Wb;
        uint4* dst = (uint4*)Ws;
        for (int i = tid; i < DIM * DIM / 8; i += 256) dst[i] = src[i];
    }
    if (tid < 128) bs[tid] = bias[tid];
    float gamma = 0.f;
    if (MODE == 2) gamma = *gammap;

    int rowBase = blockIdx.x * 32;
    int d4 = (tid & 31) * 4;
    int row = tid >> 5;  // 0..7

    for (int it = 0; it < 4; ++it) {
        int r0 = rowBase + it * 8;
        __syncthreads();
        ((float4*)Xs)[tid] = ((const float4*)(X + (size_t)r0 * DIM))[tid];
        __syncthreads();

        float a0 = bs[d4], a1 = bs[d4 + 1], a2 = bs[d4 + 2], a3 = bs[d4 + 3];
        const float* xr = &Xs[row * DIM];
#pragma unroll 8
        for (int c = 0; c < DIM; ++c) {
            float x = xr[c];
            uint2 w = *(const uint2*)&Ws[c * (DIM / 2) + (d4 >> 1)];
            a0 = fmaf(x, __uint_as_float(w.x << 16), a0);
            a1 = fmaf(x, __uint_as_float(w.x & 0xFFFF0000u), a1);
            a2 = fmaf(x, __uint_as_float(w.y << 16), a2);
            a3 = fmaf(x, __uint_as_float(w.y & 0xFFFF0000u), a3);
        }
        size_t off = (size_t)(r0 + row) * DIM + d4;
        if (MODE == 1) {
            float4 ad = *(const float4*)(add + off);
            a0 += ad.x; a1 += ad.y; a2 += ad.z; a3 += ad.w;
        }
        if (MODE == 2) {
            float4 fb = *(const float4*)(featb + off);
            a0 = fmaf(gamma, a0, fb.x);
            a1 = fmaf(gamma, a1, fb.y);
            a2 = fmaf(gamma, a2, fb.z);
            a3 = fmaf(gamma, a3, fb.w);
        }
        *(float4*)(outv + off) = make_float4(a0, a1, a2, a3);
    }
}

// ---------------------------------------------------------------- stage C
__global__ __launch_bounds__(256) void stage_c(const float4* __restrict__ pts,
                                               const int* __restrict__ idx16,
                                               const float* __restrict__ sK,
                                               const float* __restrict__ w2,
                                               const float* __restrict__ Wp1,
                                               const float* __restrict__ bp1,
                                               const float* __restrict__ Vf,
                                               float* __restrict__ vagg,
                                               float* __restrict__ hbar) {
    __shared__ float hs[4][KNN * DIM];  // 32 KB
    int wavein = threadIdx.x >> 6;
    int lid = threadIdx.x & 63;
    int p = blockIdx.x * 4 + wavein;
    int b = p >> 13;
    float4 me = pts[p];

    float wx_lo = Wp1[lid],        wx_hi = Wp1[64 + lid];
    float wy_lo = Wp1[128 + lid],  wy_hi = Wp1[192 + lid];
    float wz_lo = Wp1[256 + lid],  wz_hi = Wp1[320 + lid];
    float bl    = bp1[lid],        bh    = bp1[64 + lid];
    float w2l   = w2[lid],         w2h   = w2[64 + lid];

    int myidx = idx16[p * KNN + (lid & 15)];
    float* h = hs[wavein];
    float sc = -INFINITY;

    for (int k = 0; k < KNN; ++k) {
        int j = __shfl(myidx, k);
        int g = b * NPTS + j;
        float4 nb = pts[g];
        float rx = me.x - nb.x, ry = me.y - nb.y, rz = me.z - nb.z;
        float h_lo = fmaxf(0.f, fmaf(rx, wx_lo, fmaf(ry, wy_lo, fmaf(rz, wz_lo, bl))));
        float h_hi = fmaxf(0.f, fmaf(rx, wx_hi, fmaf(ry, wy_hi, fmaf(rz, wz_hi, bh))));
        h[k * DIM + lid] = h_lo;
        h[k * DIM + 64 + lid] = h_hi;
        float s = fmaf(h_lo, w2l, h_hi * w2h);
#pragma unroll
        for (int m = 32; m >= 1; m >>= 1) s += __shfl_xor(s, m);
        float score = s - sK[g];
        if (lid == k) sc = score;
    }
    float mx = sc;
#pragma unroll
    for (int m = 8; m >= 1; m >>= 1) mx = fmaxf(mx, __shfl_xor(mx, m));
    float e = (lid < 16) ? __expf(sc - mx) : 0.f;
    float ssum = e;
#pragma unroll
    for (int m = 8; m >= 1; m >>= 1) ssum += __shfl_xor(ssum, m);
    float a = e / ssum;

    float acc_lo = 0.f, acc_hi = 0.f, hb_lo = 0.f, hb_hi = 0.f;
    for (int k = 0; k < KNN; ++k) {
        float ak = __shfl(a, k);
        int j = __shfl(myidx, k);
        size_t g = (size_t)(b * NPTS + j) * DIM;
        acc_lo = fmaf(ak, Vf[g + lid], acc_lo);
        acc_hi = fmaf(ak, Vf[g + 64 + lid], acc_hi);
        hb_lo = fmaf(ak, h[k * DIM + lid], hb_lo);
        hb_hi = fmaf(ak, h[k * DIM + 64 + lid], hb_hi);
    }
    size_t o = (size_t)p * DIM;
    vagg[o + lid] = acc_lo;
    vagg[o + 64 + lid] = acc_hi;
    hbar[o + lid] = hb_lo;
    hbar[o + 64 + lid] = hb_hi;
}

// ---------------------------------------------------------------- launcher
extern "C" void kernel_launch(void* const* d_in, const int* in_sizes, int n_in,
                              void* d_out, int out_size, void* d_ws, size_t ws_size,
                              hipStream_t stream) {
    const float* xyz   = (const float*)d_in[0];
    const float* feat  = (const float*)d_in[1];
    // d_in[2]=Wq, d_in[3]=bq, d_in[5]=bk: provably irrelevant (softmax shift-invariance)
    const float* Wk    = (const float*)d_in[4];
    const float* Wv    = (const float*)d_in[6];
    const float* bv    = (const float*)d_in[7];
    const float* Wp1   = (const float*)d_in[8];
    const float* bp1   = (const float*)d_in[9];
    const float* Wp2   = (const float*)d_in[10];
    const float* bp2   = (const float*)d_in[11];
    const float* Wo    = (const float*)d_in[12];
    const float* bo    = (const float*)d_in[13];
    const float* gamma = (const float*)d_in[14];
    float* out = (float*)d_out;

    char* ws = (char*)d_ws;
    const size_t KB = 1024, MB = 1024 * 1024;
    float*  wk    = (float*)(ws + 0);                // 512 B
    float*  w2    = (float*)(ws + 4 * KB);           // 512 B
    float4* pts   = (float4*)(ws + 16 * KB);         // 512 KB
    float*  sKv   = (float*)(ws + 544 * KB);         // 128 KB
    u32*    Wb    = (u32*)(ws + 688 * KB);           // 96 KB (Wv|Wp2|Wo bf16)
    u64*    seeds = (u64*)(ws + 1 * MB);             // 4 MB, dead after knn_partial
    u64*    part  = (u64*)(ws + 5 * MB);             // 32 MB, dead after knn_merge
    float*  vagg  = (float*)(ws + 5 * MB);           // 16 MB, aliases dead part
    float*  hbarp = (float*)(ws + 21 * MB);          // 16 MB, aliases dead part
    int*    idx16 = (int*)(ws + 37 * MB);            // 2 MB
    float*  Vf    = (float*)(ws + 39 * MB);          // 16 MB, dead after stage_c
    float*  T1    = (float*)(ws + 39 * MB);          // aliases Vf  (total 55 MB)

    prep_weights<<<1, 256, 0, stream>>>(Wk, Wp2, wk, w2);
    conv_weights<<<96, 256, 0, stream>>>(Wv, Wp2, Wo, Wb);
    prep_points<<<NROWS / 4, 256, 0, stream>>>(xyz, feat, wk, pts, sKv);
    gemm32<0><<<1024, 256, 0, stream>>>(feat, Wb, bv, nullptr, nullptr, nullptr, Vf);
    knn_prepass<<<NROWS / 256, 256, 0, stream>>>(pts, seeds);
    knn_partial<<<(NROWS / 256) * SPLITS, 256, 0, stream>>>(pts, seeds, part);
    knn_merge<<<NROWS / 256, 256, 0, stream>>>(part, idx16);
    stage_c<<<NROWS / 4, 256, 0, stream>>>(pts, idx16, sKv, w2, Wp1, bp1, Vf, vagg, hbarp);
    gemm32<1><<<1024, 256, 0, stream>>>(hbarp, Wb + 8192, bp2, vagg, nullptr, nullptr, T1);
    gemm32<2><<<1024, 256, 0, stream>>>(T1, Wb + 16384, bo, nullptr, feat, gamma, out);
}